// Round 6
// baseline (478.057 us; speedup 1.0000x reference)
//
#include <hip/hip_runtime.h>
#include <stdint.h>

// MixLinear (LLM.int8-style): dynamic per-row quant + int8 MFMA GEMM +
// fused dequant/bias + rank-32 fp16 outlier-correction MFMA.
// R6: double-buffered global_load_lds prefetch (stage k+1 before consuming k,
// ONE barrier per K-step) to hide DMA latency under MFMA; pack+quant merged.

typedef float    f32x4  __attribute__((ext_vector_type(4)));
typedef int      i32x4  __attribute__((ext_vector_type(4)));
typedef _Float16 half8  __attribute__((ext_vector_type(8)));
typedef _Float16 half4  __attribute__((ext_vector_type(4)));

#define MTOT 8192
#define NTOT 4096
#define KTOT 4096

// LDS tile geometry: [128 rows][64 B]; 16B chunk (r,c) stored at slot c ^ SWZ(r)
#define SWZ(r) (((r) >> 1) & 3)

static __device__ __forceinline__ void gload16(const int8_t* g, int8_t* l) {
  __builtin_amdgcn_global_load_lds(
      (const __attribute__((address_space(1))) void*)g,
      (__attribute__((address_space(3))) void*)l, 16, 0, 0);
}

// ---------- kernel 1: weight pack + cache cast + per-row quant, one launch --
__global__ __launch_bounds__(256) void prep_kernel(
    const float* __restrict__ x, const int* __restrict__ ind,
    const int* __restrict__ qw32,
    int8_t* __restrict__ qx, float* __restrict__ srow, _Float16* __restrict__ xo,
    int8_t* __restrict__ qw8, _Float16* __restrict__ wch,
    const float* __restrict__ wc)
{
  const int bid = blockIdx.x;
  const int t = threadIdx.x;
  if (bid < 4096) {
    // ---- pack int32 weight row 'bid' -> int8 ----
    const int base = bid * 4096;
#pragma unroll
    for (int g = 0; g < 4; ++g) {
      const int off = g * 1024 + t * 4;
      const i32x4 v = *(const i32x4*)(qw32 + base + off);
      const uint32_t o = (uint32_t)(v[0] & 255) | ((uint32_t)(v[1] & 255) << 8) |
                         ((uint32_t)(v[2] & 255) << 16) | ((uint32_t)(v[3] & 255) << 24);
      *(uint32_t*)(qw8 + base + off) = o;
    }
  } else if (bid < 4224) {
    // ---- weight_cache f32 -> f16 (lossless: values are fp16-representable) --
    const int idx = (bid - 4096) * 1024 + t * 4;  // 128 blocks * 1024 = 131072
    const float4 v = *(const float4*)(wc + idx);
    half4 h = {(_Float16)v.x, (_Float16)v.y, (_Float16)v.z, (_Float16)v.w};
    *(half4*)(wch + idx) = h;
  } else {
    // ---- dynamic per-row quant, one wave per row ----
    const int w = t >> 6, l = t & 63;
    const int row = (bid - 4224) * 4 + w;
    const float* xrow = x + (size_t)row * KTOT;
    const float4* xr = (const float4*)xrow;

    float4 v[16];
#pragma unroll
    for (int g = 0; g < 16; ++g) v[g] = xr[g * 64 + l];  // coalesced, 16-deep ILP

    float am = 0.f;
#pragma unroll
    for (int g = 0; g < 16; ++g)
      am = fmaxf(am, fmaxf(fmaxf(fabsf(v[g].x), fabsf(v[g].y)),
                           fmaxf(fabsf(v[g].z), fabsf(v[g].w))));
#pragma unroll
    for (int off = 32; off; off >>= 1)
      am = fmaxf(am, __shfl_xor(am, off, 64));

    const float rscale = 127.0f / am;
    uint32_t* qrow = (uint32_t*)(qx + (size_t)row * KTOT);
#pragma unroll
    for (int g = 0; g < 16; ++g) {
      const float4 u = v[g];
      const int q0 = (int)rintf(fminf(fmaxf(u.x * rscale, -128.f), 127.f));
      const int q1 = (int)rintf(fminf(fmaxf(u.y * rscale, -128.f), 127.f));
      const int q2 = (int)rintf(fminf(fmaxf(u.z * rscale, -128.f), 127.f));
      const int q3 = (int)rintf(fminf(fmaxf(u.w * rscale, -128.f), 127.f));
      qrow[g * 64 + l] = (uint32_t)(q0 & 255) | ((uint32_t)(q1 & 255) << 8) |
                         ((uint32_t)(q2 & 255) << 16) | ((uint32_t)(q3 & 255) << 24);
    }
    if (l < 32) xo[row * 32 + l] = (_Float16)xrow[ind[l]];
    if (l == 0) srow[row] = am / 127.0f;
  }
}

// ---------- kernel 2: int8 GEMM + dequant + bias + fp16 outlier MFMA -------
// 128x128 tile, 4 waves 2x2, each wave 64x64 via 4x4 mfma_i32_16x16x64_i8.
// Double-buffered LDS: stage tile k+1 via global_load_lds while MFMAing tile k;
// single __syncthreads per K-step (its vmcnt/lgkm drain overlaps compute).
__global__ __launch_bounds__(256) void mixgemm_kernel(
    const int8_t* __restrict__ qx, const int8_t* __restrict__ qw,
    const float* __restrict__ srow, const float* __restrict__ sc,
    const _Float16* __restrict__ xo, const _Float16* __restrict__ wc,
    float* __restrict__ out)
{
  __shared__ int8_t lA[2][8192];
  __shared__ int8_t lB[2][8192];

  const int t = threadIdx.x;
  const int lane = t & 63;
  const int wid = t >> 6;
  const int wm = wid >> 1, wn = wid & 1;

  // XCD-aware bijective swizzle: 2048 blocks = 8 XCDs x 256
  const int bid = blockIdx.x;
  const int swz = (bid & 7) * 256 + (bid >> 3);
  const int tn = swz & 31;   // NTOT/128 = 32
  const int tm = swz >> 5;
  const int bm0 = tm * 128, bn0 = tn * 128;

  // gload_lds staging: wave w fills LDS bytes [w*2048, w*2048+2048) of each
  // tile via 2 instrs (lane l -> base + 16*l). Linear chunk i = w*128+j*64+l,
  // row r = i>>2, slot s = i&3; source chunk col = s ^ SWZ(r).
  const int rst = wid * 32 + (lane >> 2);            // row for j=0 (j=1: +16)
  const int cst = ((lane & 3) ^ SWZ(rst)) * 16;      // SWZ invariant under r+16
  const int8_t* gA0 = qx + (size_t)(bm0 + rst) * KTOT + cst;
  const int8_t* gB0 = qw + (size_t)(bn0 + rst) * KTOT + cst;
  const int wo = wid * 2048;

  // fragment ds_read offsets (A rows = wave M strip, B rows = wave N strip)
  int roA[4], roB[4];
#pragma unroll
  for (int i = 0; i < 4; ++i) {
    const int ra = wm * 64 + i * 16 + (lane & 15);
    roA[i] = ra * 64 + (((lane >> 4) ^ SWZ(ra)) * 16);
    const int rb = wn * 64 + i * 16 + (lane & 15);
    roB[i] = rb * 64 + (((lane >> 4) ^ SWZ(rb)) * 16);
  }

  i32x4 acc[4][4];
#pragma unroll
  for (int i = 0; i < 4; ++i)
#pragma unroll
    for (int j = 0; j < 4; ++j) acc[i][j] = i32x4{0, 0, 0, 0};

  // prologue: stage tile 0 into buffer 0
  gload16(gA0, lA[0] + wo);
  gload16(gA0 + 16 * KTOT, lA[0] + wo + 1024);
  gload16(gB0, lB[0] + wo);
  gload16(gB0 + 16 * KTOT, lB[0] + wo + 1024);
  __syncthreads();  // compiler drains vmcnt(0) here

  int cur = 0;
  for (int kt = 64; kt < KTOT; kt += 64) {
    const int nxt = cur ^ 1;
    // stage tile kt into the other buffer — in flight during this tile's MFMA
    gload16(gA0 + kt, lA[nxt] + wo);
    gload16(gA0 + kt + 16 * KTOT, lA[nxt] + wo + 1024);
    gload16(gB0 + kt, lB[nxt] + wo);
    gload16(gB0 + kt + 16 * KTOT, lB[nxt] + wo + 1024);
    // consume current buffer
    i32x4 af[4], bfr[4];
#pragma unroll
    for (int i = 0; i < 4; ++i) {
      af[i]  = *(const i32x4*)(lA[cur] + roA[i]);
      bfr[i] = *(const i32x4*)(lB[cur] + roB[i]);
    }
#pragma unroll
    for (int i = 0; i < 4; ++i)
#pragma unroll
      for (int j = 0; j < 4; ++j)
        acc[i][j] = __builtin_amdgcn_mfma_i32_16x16x64_i8(af[i], bfr[j], acc[i][j], 0, 0, 0);
    __syncthreads();  // one barrier per K-step: drains DMA + orders buffer reuse
    cur = nxt;
  }
  // epilogue tile (last K-step, already staged)
  {
    i32x4 af[4], bfr[4];
#pragma unroll
    for (int i = 0; i < 4; ++i) {
      af[i]  = *(const i32x4*)(lA[cur] + roA[i]);
      bfr[i] = *(const i32x4*)(lB[cur] + roB[i]);
    }
#pragma unroll
    for (int i = 0; i < 4; ++i)
#pragma unroll
      for (int j = 0; j < 4; ++j)
        acc[i][j] = __builtin_amdgcn_mfma_i32_16x16x64_i8(af[i], bfr[j], acc[i][j], 0, 0, 0);
  }

  // ---- outlier correction: corr = xo_tile (128x32 f16) @ wc_tile^T ----
  // xo/wc tiles are contiguous 8 KB blobs with identical [128][64B] geometry.
  {
    const int idx0 = t, idx1 = t + 256;
    const int r0 = idx0 >> 2, c0 = idx0 & 3;
    const int r1 = idx1 >> 2, c1 = idx1 & 3;
    const int w0 = r0 * 64 + ((c0 ^ SWZ(r0)) * 16);
    const int w1 = r1 * 64 + ((c1 ^ SWZ(r1)) * 16);
    const char* xob = (const char*)xo + (size_t)bm0 * 64;
    const char* wcb = (const char*)wc + (size_t)bn0 * 64;
    const i32x4 xs0 = *(const i32x4*)(xob + idx0 * 16);
    const i32x4 xs1 = *(const i32x4*)(xob + idx1 * 16);
    const i32x4 ws0 = *(const i32x4*)(wcb + idx0 * 16);
    const i32x4 ws1 = *(const i32x4*)(wcb + idx1 * 16);
    __syncthreads();  // last K-step's ds_reads done before overwrite
    *(i32x4*)(lA[0] + w0) = xs0;
    *(i32x4*)(lA[0] + w1) = xs1;
    *(i32x4*)(lB[0] + w0) = ws0;
    *(i32x4*)(lB[0] + w1) = ws1;
    __syncthreads();
  }
  f32x4 corr[4][4];
#pragma unroll
  for (int i = 0; i < 4; ++i)
#pragma unroll
    for (int j = 0; j < 4; ++j) corr[i][j] = f32x4{0.f, 0.f, 0.f, 0.f};
  {
    half8 xf[4], wf[4];
#pragma unroll
    for (int i = 0; i < 4; ++i) {
      xf[i] = __builtin_bit_cast(half8, *(const i32x4*)(lA[0] + roA[i]));
      wf[i] = __builtin_bit_cast(half8, *(const i32x4*)(lB[0] + roB[i]));
    }
#pragma unroll
    for (int i = 0; i < 4; ++i)
#pragma unroll
      for (int j = 0; j < 4; ++j)
        corr[i][j] = __builtin_amdgcn_mfma_f32_16x16x32_f16(xf[i], wf[j], corr[i][j], 0, 0, 0);
  }

  // ---- epilogue: y = acc*srow*wscale + bias + corr, store f32 ----
#pragma unroll
  for (int i = 0; i < 4; ++i) {
    const int rowg = bm0 + wm * 64 + i * 16 + (lane >> 4) * 4;
    const f32x4 sr = *(const f32x4*)(srow + rowg);
#pragma unroll
    for (int j = 0; j < 4; ++j) {
      const int colg = bn0 + wn * 64 + j * 16 + (lane & 15);
      const float2 scb = ((const float2*)sc)[colg];  // [scale, bias]
      float* op = out + (size_t)rowg * NTOT + colg;
#pragma unroll
      for (int r = 0; r < 4; ++r) {
        const float y = (float)acc[i][j][r] * (sr[r] * scb.x) + scb.y + corr[i][j][r];
        op[(size_t)r * NTOT] = y;
      }
    }
  }
}

extern "C" void kernel_launch(void* const* d_in, const int* in_sizes, int n_in,
                              void* d_out, int out_size, void* d_ws, size_t ws_size,
                              hipStream_t stream) {
  (void)in_sizes; (void)n_in; (void)out_size; (void)ws_size;
  const float* x    = (const float*)d_in[0];   // f32 [2,4096,4096] (fp16 values)
  const int*   qw32 = (const int*)d_in[1];     // int32 [4096,4096] (int8 values)
  const float* sc   = (const float*)d_in[2];   // f32 [4096,2] (scale,bias)
  const float* wcf  = (const float*)d_in[3];   // f32 [4096,32]
  const int*   ind  = (const int*)d_in[4];     // int32 [32]
  float* out = (float*)d_out;

  char* ws = (char*)d_ws;
  int8_t*   qx   = (int8_t*)ws;                          // 32 MB
  float*    srow = (float*)(ws + 33554432);              // 32 KB
  _Float16* xo   = (_Float16*)(ws + 33587200);           // 512 KB
  int8_t*   qw8  = (int8_t*)(ws + 34111488);             // 16 MB
  _Float16* wch  = (_Float16*)(ws + 50888704);           // 256 KB

  prep_kernel<<<4224 + MTOT / 4, 256, 0, stream>>>(x, ind, qw32, qx, srow, xo, qw8, wch, wcf);
  mixgemm_kernel<<<(MTOT / 128) * (NTOT / 128), 256, 0, stream>>>(qx, qw8, srow, sc, xo, wch, out);
}

// Round 7
// 425.822 us; speedup vs baseline: 1.1227x; 1.1227x over previous
//
#include <hip/hip_runtime.h>
#include <stdint.h>

// MixLinear (LLM.int8-style): dynamic per-row quant + int8 MFMA GEMM +
// fused dequant/bias + rank-32 fp16 outlier-correction MFMA.
// R7: BK=128 single-buffer (2 barriers per K-step, 32 steps) — amortize the
// vmcnt(0) barrier drain over 2x MFMA work. R6's dbuf regressed (drain only
// covered ~82cyc of MFMA while LDS doubling cut block co-residency).

typedef float    f32x4  __attribute__((ext_vector_type(4)));
typedef int      i32x4  __attribute__((ext_vector_type(4)));
typedef _Float16 half8  __attribute__((ext_vector_type(8)));
typedef _Float16 half4  __attribute__((ext_vector_type(4)));

#define MTOT 8192
#define NTOT 4096
#define KTOT 4096

// main-loop LDS tile: [128 rows][128 B]; 16B chunk (r,c) at slot c ^ (r&7)
// corr LDS tile:      [128 rows][64 B];  16B chunk (r,c) at slot c ^ SWZ4(r)
#define SWZ4(r) (((r) >> 1) & 3)

static __device__ __forceinline__ void gload16(const int8_t* g, int8_t* l) {
  __builtin_amdgcn_global_load_lds(
      (const __attribute__((address_space(1))) void*)g,
      (__attribute__((address_space(3))) void*)l, 16, 0, 0);
}

// ---------- kernel 1: weight pack + cache cast + per-row quant, one launch --
__global__ __launch_bounds__(256) void prep_kernel(
    const float* __restrict__ x, const int* __restrict__ ind,
    const int* __restrict__ qw32,
    int8_t* __restrict__ qx, float* __restrict__ srow, _Float16* __restrict__ xo,
    int8_t* __restrict__ qw8, _Float16* __restrict__ wch,
    const float* __restrict__ wc)
{
  const int bid = blockIdx.x;
  const int t = threadIdx.x;
  if (bid < 4096) {
    // ---- pack int32 weight row 'bid' -> int8 ----
    const int base = bid * 4096;
#pragma unroll
    for (int g = 0; g < 4; ++g) {
      const int off = g * 1024 + t * 4;
      const i32x4 v = *(const i32x4*)(qw32 + base + off);
      const uint32_t o = (uint32_t)(v[0] & 255) | ((uint32_t)(v[1] & 255) << 8) |
                         ((uint32_t)(v[2] & 255) << 16) | ((uint32_t)(v[3] & 255) << 24);
      *(uint32_t*)(qw8 + base + off) = o;
    }
  } else if (bid < 4224) {
    // ---- weight_cache f32 -> f16 (lossless: values are fp16-representable) --
    const int idx = (bid - 4096) * 1024 + t * 4;  // 128 blocks * 1024 = 131072
    const float4 v = *(const float4*)(wc + idx);
    half4 h = {(_Float16)v.x, (_Float16)v.y, (_Float16)v.z, (_Float16)v.w};
    *(half4*)(wch + idx) = h;
  } else {
    // ---- dynamic per-row quant, one wave per row ----
    const int w = t >> 6, l = t & 63;
    const int row = (bid - 4224) * 4 + w;
    const float* xrow = x + (size_t)row * KTOT;
    const float4* xr = (const float4*)xrow;

    float4 v[16];
#pragma unroll
    for (int g = 0; g < 16; ++g) v[g] = xr[g * 64 + l];  // coalesced, 16-deep ILP

    float am = 0.f;
#pragma unroll
    for (int g = 0; g < 16; ++g)
      am = fmaxf(am, fmaxf(fmaxf(fabsf(v[g].x), fabsf(v[g].y)),
                           fmaxf(fabsf(v[g].z), fabsf(v[g].w))));
#pragma unroll
    for (int off = 32; off; off >>= 1)
      am = fmaxf(am, __shfl_xor(am, off, 64));

    const float rscale = 127.0f / am;
    uint32_t* qrow = (uint32_t*)(qx + (size_t)row * KTOT);
#pragma unroll
    for (int g = 0; g < 16; ++g) {
      const float4 u = v[g];
      const int q0 = (int)rintf(fminf(fmaxf(u.x * rscale, -128.f), 127.f));
      const int q1 = (int)rintf(fminf(fmaxf(u.y * rscale, -128.f), 127.f));
      const int q2 = (int)rintf(fminf(fmaxf(u.z * rscale, -128.f), 127.f));
      const int q3 = (int)rintf(fminf(fmaxf(u.w * rscale, -128.f), 127.f));
      qrow[g * 64 + l] = (uint32_t)(q0 & 255) | ((uint32_t)(q1 & 255) << 8) |
                         ((uint32_t)(q2 & 255) << 16) | ((uint32_t)(q3 & 255) << 24);
    }
    if (l < 32) xo[row * 32 + l] = (_Float16)xrow[ind[l]];
    if (l == 0) srow[row] = am / 127.0f;
  }
}

// ---------- kernel 2: int8 GEMM + dequant + bias + fp16 outlier MFMA -------
// 128x128 tile, BK=128, 4 waves 2x2, each wave 64x64; 32 MFMA + 16 ds_read
// per barrier pair. Staging: global_load_lds dwordx4, linear LDS dest,
// source pre-swizzled so LDS slot (r, c^(r&7)) holds global chunk (r, c).
__global__ __launch_bounds__(256) void mixgemm_kernel(
    const int8_t* __restrict__ qx, const int8_t* __restrict__ qw,
    const float* __restrict__ srow, const float* __restrict__ sc,
    const _Float16* __restrict__ xo, const _Float16* __restrict__ wc,
    float* __restrict__ out)
{
  __shared__ int8_t lA[128 * 128];
  __shared__ int8_t lB[128 * 128];

  const int t = threadIdx.x;
  const int lane = t & 63;
  const int wid = t >> 6;
  const int wm = wid >> 1, wn = wid & 1;

  // XCD-aware bijective swizzle: 2048 blocks = 8 XCDs x 256
  const int bid = blockIdx.x;
  const int swz = (bid & 7) * 256 + (bid >> 3);
  const int tn = swz & 31;   // NTOT/128 = 32
  const int tm = swz >> 5;
  const int bm0 = tm * 128, bn0 = tn * 128;

  // Staging: per tile 1024 chunks of 16B; wave w covers rows [w*32, w*32+32)
  // via 4 instrs of 8 rows each. Lane l -> row w*32 + instr*8 + (l>>3),
  // LDS slot l&7; source chunk col = (l&7) ^ (l>>3)  (r&7 == l>>3).
  const int rst = wid * 32 + (lane >> 3);
  const int cst = ((lane & 7) ^ (lane >> 3)) * 16;
  const int8_t* gA0 = qx + (size_t)(bm0 + rst) * KTOT + cst;
  const int8_t* gB0 = qw + (size_t)(bn0 + rst) * KTOT + cst;
  int8_t* dA = lA + wid * 4096;
  int8_t* dB = lB + wid * 4096;

  // fragment ds_read offsets for kk=0 (kk=1: XOR 64 — chunk bit2 flip)
  int roA[4], roB[4];
#pragma unroll
  for (int i = 0; i < 4; ++i) {
    const int ra = wm * 64 + i * 16 + (lane & 15);
    roA[i] = ra * 128 + (((lane >> 4) ^ (ra & 7)) * 16);
    const int rb = wn * 64 + i * 16 + (lane & 15);
    roB[i] = rb * 128 + (((lane >> 4) ^ (rb & 7)) * 16);
  }

  i32x4 acc[4][4];
#pragma unroll
  for (int i = 0; i < 4; ++i)
#pragma unroll
    for (int j = 0; j < 4; ++j) acc[i][j] = i32x4{0, 0, 0, 0};

  for (int kt = 0; kt < KTOT; kt += 128) {
    __syncthreads();  // previous step's ds_reads done before DMA overwrite
#pragma unroll
    for (int s = 0; s < 4; ++s) {
      gload16(gA0 + kt + (size_t)s * 8 * KTOT, dA + s * 1024);
      gload16(gB0 + kt + (size_t)s * 8 * KTOT, dB + s * 1024);
    }
    __syncthreads();  // compiler drains vmcnt(0) here — tile resident
#pragma unroll
    for (int kk = 0; kk < 2; ++kk) {
      const int xk = kk * 64;
      i32x4 af[4], bfr[4];
#pragma unroll
      for (int i = 0; i < 4; ++i) {
        af[i]  = *(const i32x4*)(lA + (roA[i] ^ xk));
        bfr[i] = *(const i32x4*)(lB + (roB[i] ^ xk));
      }
#pragma unroll
      for (int i = 0; i < 4; ++i)
#pragma unroll
        for (int j = 0; j < 4; ++j)
          acc[i][j] = __builtin_amdgcn_mfma_i32_16x16x64_i8(af[i], bfr[j], acc[i][j], 0, 0, 0);
    }
  }

  // ---- outlier correction: corr = xo_tile (128x32 f16) @ wc_tile^T ----
  // xo/wc tiles are contiguous 8 KB blobs, staged in [128][64B] layout with
  // SWZ4 chunk swizzle (independent of the main loop's geometry).
  {
    const int idx0 = t, idx1 = t + 256;
    const int r0 = idx0 >> 2, c0 = idx0 & 3;
    const int r1 = idx1 >> 2, c1 = idx1 & 3;
    const int w0 = r0 * 64 + ((c0 ^ SWZ4(r0)) * 16);
    const int w1 = r1 * 64 + ((c1 ^ SWZ4(r1)) * 16);
    const char* xob = (const char*)xo + (size_t)bm0 * 64;
    const char* wcb = (const char*)wc + (size_t)bn0 * 64;
    const i32x4 xs0 = *(const i32x4*)(xob + idx0 * 16);
    const i32x4 xs1 = *(const i32x4*)(xob + idx1 * 16);
    const i32x4 ws0 = *(const i32x4*)(wcb + idx0 * 16);
    const i32x4 ws1 = *(const i32x4*)(wcb + idx1 * 16);
    __syncthreads();  // last K-step's ds_reads done before overwrite
    *(i32x4*)(lA + w0) = xs0;
    *(i32x4*)(lA + w1) = xs1;
    *(i32x4*)(lB + w0) = ws0;
    *(i32x4*)(lB + w1) = ws1;
    __syncthreads();
  }
  f32x4 corr[4][4];
#pragma unroll
  for (int i = 0; i < 4; ++i)
#pragma unroll
    for (int j = 0; j < 4; ++j) corr[i][j] = f32x4{0.f, 0.f, 0.f, 0.f};
  {
    half8 xf[4], wf[4];
#pragma unroll
    for (int i = 0; i < 4; ++i) {
      const int ra = wm * 64 + i * 16 + (lane & 15);
      const int rb = wn * 64 + i * 16 + (lane & 15);
      const int oA = ra * 64 + (((lane >> 4) ^ SWZ4(ra)) * 16);
      const int oB = rb * 64 + (((lane >> 4) ^ SWZ4(rb)) * 16);
      xf[i] = __builtin_bit_cast(half8, *(const i32x4*)(lA + oA));
      wf[i] = __builtin_bit_cast(half8, *(const i32x4*)(lB + oB));
    }
#pragma unroll
    for (int i = 0; i < 4; ++i)
#pragma unroll
      for (int j = 0; j < 4; ++j)
        corr[i][j] = __builtin_amdgcn_mfma_f32_16x16x32_f16(xf[i], wf[j], corr[i][j], 0, 0, 0);
  }

  // ---- epilogue: y = acc*srow*wscale + bias + corr, store f32 ----
#pragma unroll
  for (int i = 0; i < 4; ++i) {
    const int rowg = bm0 + wm * 64 + i * 16 + (lane >> 4) * 4;
    const f32x4 sr = *(const f32x4*)(srow + rowg);
#pragma unroll
    for (int j = 0; j < 4; ++j) {
      const int colg = bn0 + wn * 64 + j * 16 + (lane & 15);
      const float2 scb = ((const float2*)sc)[colg];  // [scale, bias]
      float* op = out + (size_t)rowg * NTOT + colg;
#pragma unroll
      for (int r = 0; r < 4; ++r) {
        const float y = (float)acc[i][j][r] * (sr[r] * scb.x) + scb.y + corr[i][j][r];
        op[(size_t)r * NTOT] = y;
      }
    }
  }
}

extern "C" void kernel_launch(void* const* d_in, const int* in_sizes, int n_in,
                              void* d_out, int out_size, void* d_ws, size_t ws_size,
                              hipStream_t stream) {
  (void)in_sizes; (void)n_in; (void)out_size; (void)ws_size;
  const float* x    = (const float*)d_in[0];   // f32 [2,4096,4096] (fp16 values)
  const int*   qw32 = (const int*)d_in[1];     // int32 [4096,4096] (int8 values)
  const float* sc   = (const float*)d_in[2];   // f32 [4096,2] (scale,bias)
  const float* wcf  = (const float*)d_in[3];   // f32 [4096,32]
  const int*   ind  = (const int*)d_in[4];     // int32 [32]
  float* out = (float*)d_out;

  char* ws = (char*)d_ws;
  int8_t*   qx   = (int8_t*)ws;                          // 32 MB
  float*    srow = (float*)(ws + 33554432);              // 32 KB
  _Float16* xo   = (_Float16*)(ws + 33587200);           // 512 KB
  int8_t*   qw8  = (int8_t*)(ws + 34111488);             // 16 MB
  _Float16* wch  = (_Float16*)(ws + 50888704);           // 256 KB

  prep_kernel<<<4224 + MTOT / 4, 256, 0, stream>>>(x, ind, qw32, qx, srow, xo, qw8, wch, wcf);
  mixgemm_kernel<<<(MTOT / 128) * (NTOT / 128), 256, 0, stream>>>(qx, qw8, srow, sc, xo, wch, out);
}